// Round 5
// baseline (541.713 us; speedup 1.0000x reference)
//
#include <hip/hip_runtime.h>
#include <hip/hip_bf16.h>

// Problem constants
#define BSZ   512
#define ENCD  2048
#define DECD  1024
#define TST   12
#define PREDT 24
#define INDIM 2061
#define KPAD  2112      // INDIM padded to multiple of 64
#define G4    4096      // 4*DEC
#define KH    24576     // DEC*PRED

typedef __attribute__((ext_vector_type(8))) short s8v;
typedef __attribute__((ext_vector_type(4))) short s4v;
typedef __attribute__((ext_vector_type(4))) float f4v;

__device__ __forceinline__ short bf16_of(float f) {
  union { float f; unsigned u; } x; x.f = f;
  unsigned r = x.u + 0x7fffu + ((x.u >> 16) & 1u);  // RNE
  return (short)(r >> 16);
}
__device__ __forceinline__ float sigf(float x) { return 1.f / (1.f + __expf(-x)); }
// tanh(x) = 1 - 2/(exp(2x)+1): no NaN for large |x|
__device__ __forceinline__ float tanh_(float x) { return 1.f - 2.f / (1.f + __expf(2.f * x)); }

// LDS swizzle: row stride 128 B (BK=64 bf16). XOR row-bits into 16B-slot index.
__device__ __forceinline__ int lds_off(int row, int colb) {
  return row * 128 + (colb ^ ((row & 7) << 4));
}

// ---------------- prep kernels ----------------

__global__ void prep_x(const float* __restrict__ enc, const float* __restrict__ oni,
                       const float* __restrict__ ssi, short* __restrict__ x_bf) {
  int idx = blockIdx.x * 256 + threadIdx.x;
  if (idx >= BSZ * KPAD) return;
  int b = idx / KPAD, k = idx % KPAD;
  float v = 0.f;
  if (k < ENCD) v = enc[b * ENCD + k];
  else if (k == ENCD) v = oni[b];
  else if (k < INDIM) v = ssi[b * TST + (k - ENCD - 1)];
  x_bf[idx] = bf16_of(v);
}

// W_ih (4096 x 2061 fp32) -> permuted, padded bf16 [dblk 64][gate 4][dl 16][k 2112]
__global__ void prep_wih(const float* __restrict__ W, short* __restrict__ o) {
  int idx = blockIdx.x * 256 + threadIdx.x;      // over 4096*2112
  int rp = idx / KPAD; int k = idx - rp * KPAD;
  int dblk = rp >> 6, rem = rp & 63, g = rem >> 4, dl = rem & 15;
  int srow = g * 1024 + dblk * 16 + dl;
  float v = (k < INDIM) ? W[(size_t)srow * INDIM + k] : 0.f;
  o[idx] = bf16_of(v);
}

// W_hh (4096 x 1024 fp32) -> permuted bf16 [dblk 64][gate 4][dl 16][k 1024]
__global__ void prep_whh(const float* __restrict__ W, short* __restrict__ o) {
  int idx = blockIdx.x * 256 + threadIdx.x;      // over 4096*1024
  int rp = idx >> 10; int k = idx & 1023;
  int dblk = rp >> 6, rem = rp & 63, g = rem >> 4, dl = rem & 15;
  int srow = g * 1024 + dblk * 16 + dl;
  o[idx] = bf16_of(W[(size_t)srow * 1024 + k]);
}

// ---------------- x_proj GEMM ----------------
// xp_p[512][4096 permuted] = x(512x2112) @ wih_bf^T + b_ih + b_hh
__global__ __launch_bounds__(256, 1) void xproj_k(
    const short* __restrict__ x_bf, const short* __restrict__ wih_bf,
    const float* __restrict__ b_ih, const float* __restrict__ b_hh,
    float* __restrict__ xp_p) {
  __shared__ __align__(16) char sA[2][16384];
  __shared__ __align__(16) char sB[2][8192];
  int tid = threadIdx.x, lane = tid & 63, w = tid >> 6;
  int L = blockIdx.x;
  int bm = L >> 6, pb = (L & 7) * 8 + ((L >> 3) & 7);
  const int l4 = lane & 15, lg = lane >> 4;

  s8v aR[4], bR[2];
  auto LOAD = [&](int kt) {
    int kk = kt * 64;
#pragma unroll
    for (int i = 0; i < 4; ++i) {
      int c = tid + i * 256, r = c >> 3, sl = c & 7;
      aR[i] = *(const s8v*)(x_bf + (size_t)(bm * 128 + r) * KPAD + kk + sl * 8);
    }
#pragma unroll
    for (int i = 0; i < 2; ++i) {
      int c = tid + i * 256, r = c >> 3, sl = c & 7;
      bR[i] = *(const s8v*)(wih_bf + (size_t)(pb * 64 + r) * KPAD + kk + sl * 8);
    }
  };
  auto WRITE = [&](int buf) {
#pragma unroll
    for (int i = 0; i < 4; ++i) {
      int c = tid + i * 256, r = c >> 3, sl = c & 7;
      *(s8v*)(sA[buf] + lds_off(r, sl * 16)) = aR[i];
    }
#pragma unroll
    for (int i = 0; i < 2; ++i) {
      int c = tid + i * 256, r = c >> 3, sl = c & 7;
      *(s8v*)(sB[buf] + lds_off(r, sl * 16)) = bR[i];
    }
  };

  f4v acc[2][4] = {};
  LOAD(0); WRITE(0); LOAD(1);
  __syncthreads();
  for (int kt = 0; kt < 33; ++kt) {
    int cur = kt & 1;
    if (kt < 32) WRITE(cur ^ 1);
    if (kt < 31) LOAD(kt + 2);
#pragma unroll
    for (int ks = 0; ks < 2; ++ks) {
      int colb = ks * 64 + lg * 16;
      s8v af[2], bf[4];
#pragma unroll
      for (int mi = 0; mi < 2; ++mi)
        af[mi] = *(const s8v*)(sA[cur] + lds_off(w * 32 + mi * 16 + l4, colb));
#pragma unroll
      for (int ni = 0; ni < 4; ++ni)
        bf[ni] = *(const s8v*)(sB[cur] + lds_off(ni * 16 + l4, colb));
#pragma unroll
      for (int mi = 0; mi < 2; ++mi)
#pragma unroll
        for (int ni = 0; ni < 4; ++ni)
          acc[mi][ni] = __builtin_amdgcn_mfma_f32_16x16x32_bf16(af[mi], bf[ni], acc[mi][ni], 0, 0, 0);
    }
    __syncthreads();
  }
#pragma unroll
  for (int ni = 0; ni < 4; ++ni) {
    int src = ni * 1024 + pb * 16 + l4;
    float bv = b_ih[src] + b_hh[src];
#pragma unroll
    for (int mi = 0; mi < 2; ++mi)
#pragma unroll
      for (int j = 0; j < 4; ++j) {
        int row = bm * 128 + w * 32 + mi * 16 + lg * 4 + j;
        xp_p[(size_t)row * G4 + pb * 64 + ni * 16 + l4] = acc[mi][ni][j] + bv;
      }
  }
}

// ---------------- LSTM step v2 (one launch per t) ----------------
// grid (8 bm, 64 cp); block 256 = 4 waves: kg = w>>1 (K-half), ow = w&1 (32-row half)
// wave tile: 32 r x 64 gate-cols over K-half 512 (8 kt of 64).
// A (h) loaded DIRECTLY global->MFMA-frag registers (no LDS, no A barriers).
// B double-buffered in LDS per kg. fp32 split-K combine via LDS, then fused cell.
template <bool FIRST>
__global__ __launch_bounds__(256, 2) void step_k(
    const short* __restrict__ h_in, const short* __restrict__ whh_bf,
    const float* __restrict__ xp_p, float* __restrict__ c_st,
    short* __restrict__ h_out, short* __restrict__ hs_t, int tstep) {
  __shared__ __align__(16) char sB[32768];   // [kg 2][buf 2][8KB B tile] ; gates tile reuses
  __shared__ __align__(16) char sX[16384];   // kg1 acc dump (2 ow x 8KB)
  int tid = threadIdx.x, lane = tid & 63, w = tid >> 6;
  int kg = w >> 1, ow = w & 1;
  int bm = blockIdx.x, cp = blockIdx.y;
  const int l4 = lane & 15, lg = lane >> 4;

  f4v acc[2][4] = {};

  if (!FIRST) {
    const short* bbase = whh_bf + (size_t)cp * 64 * DECD + kg * 512;
    const short* abase = h_in + (size_t)(bm * 64 + ow * 32) * DECD + kg * 512;
    char* myB = sB + kg * 16384;
    int lc = tid & 127;
    s8v st[4];
    auto LOADB = [&](int kt) {
#pragma unroll
      for (int i = 0; i < 4; ++i) {
        int c = lc + i * 128, r = c >> 3, sl = c & 7;
        st[i] = *(const s8v*)(bbase + (size_t)r * DECD + kt * 64 + sl * 8);
      }
    };
    auto WRITEB = [&](int buf) {
      char* p = myB + buf * 8192;
#pragma unroll
      for (int i = 0; i < 4; ++i) {
        int c = lc + i * 128, r = c >> 3, sl = c & 7;
        *(s8v*)(p + lds_off(r, sl * 16)) = st[i];
      }
    };
    LOADB(0); WRITEB(0); LOADB(1);
    __syncthreads();
    for (int kt = 0; kt < 8; ++kt) {
      int cur = kt & 1;
      if (kt < 7) WRITEB(cur ^ 1);
      if (kt < 6) LOADB(kt + 2);
      char* p = myB + cur * 8192;
#pragma unroll
      for (int ks = 0; ks < 2; ++ks) {
        s8v af[2], bf[4];
#pragma unroll
        for (int mi = 0; mi < 2; ++mi)
          af[mi] = *(const s8v*)(abase + (size_t)(mi * 16 + l4) * DECD + kt * 64 + ks * 32 + lg * 8);
#pragma unroll
        for (int ni = 0; ni < 4; ++ni)
          bf[ni] = *(const s8v*)(p + lds_off(ni * 16 + l4, ks * 64 + lg * 16));
#pragma unroll
        for (int mi = 0; mi < 2; ++mi)
#pragma unroll
          for (int ni = 0; ni < 4; ++ni)
            acc[mi][ni] = __builtin_amdgcn_mfma_f32_16x16x32_bf16(af[mi], bf[ni], acc[mi][ni], 0, 0, 0);
      }
      __syncthreads();
    }
    // split-K combine: kg1 dumps acc; kg0 adds, writes gate tile (fp32, swizzled)
    if (kg == 1) {
#pragma unroll
      for (int mi = 0; mi < 2; ++mi)
#pragma unroll
        for (int ni = 0; ni < 4; ++ni)
#pragma unroll
          for (int j = 0; j < 4; ++j)
            *(float*)(sX + ow * 8192 + ((mi * 4 + ni) * 4 + j) * 256 + lane * 4) = acc[mi][ni][j];
    }
    __syncthreads();
    if (kg == 0) {
#pragma unroll
      for (int mi = 0; mi < 2; ++mi)
#pragma unroll
        for (int ni = 0; ni < 4; ++ni) {
#pragma unroll
          for (int j = 0; j < 4; ++j) {
            float v = acc[mi][ni][j] +
                      *(const float*)(sX + ow * 8192 + ((mi * 4 + ni) * 4 + j) * 256 + lane * 4);
            int row = ow * 32 + mi * 16 + lg * 4 + j;
            int col = ni * 16 + l4;
            *(float*)(sB + row * 256 + ((col ^ ((row & 3) << 4)) * 4)) = v;
          }
        }
    }
    __syncthreads();
  }

  // fused cell: 64 r x 16 d per block, 4 cells/thread
#pragma unroll
  for (int q = 0; q < 4; ++q) {
    int idx = tid + q * 256;
    int r = idx >> 4, dl = idx & 15;
    int row = bm * 64 + r;
    size_t xb = (size_t)row * G4 + cp * 64 + dl;
    float g0 = 0.f, g1 = 0.f, g2 = 0.f, g3 = 0.f;
    if (!FIRST) {
      int sw = (r & 3) << 4;
      g0 = *(const float*)(sB + r * 256 + (((0  + dl) ^ sw) * 4));
      g1 = *(const float*)(sB + r * 256 + (((16 + dl) ^ sw) * 4));
      g2 = *(const float*)(sB + r * 256 + (((32 + dl) ^ sw) * 4));
      g3 = *(const float*)(sB + r * 256 + (((48 + dl) ^ sw) * 4));
    }
    float gi = g0 + xp_p[xb];
    float gf = g1 + xp_p[xb + 16];
    float gg = g2 + xp_p[xb + 32];
    float go = g3 + xp_p[xb + 48];
    int d = cp * 16 + dl;
    size_t cd = (size_t)row * DECD + d;
    float c_old = FIRST ? 0.f : c_st[cd];
    float cn = sigf(gf) * c_old + sigf(gi) * tanh_(gg);
    c_st[cd] = cn;
    float h = sigf(go) * tanh_(cn);
    short hb = bf16_of(h);
    if (tstep < 23) h_out[cd] = hb;
    hs_t[(size_t)tstep * (BSZ * DECD) + cd] = hb;
  }
}

// ---------------- transpose: hs_t[t][row][d] -> hs[row][d*24+t] ----------------
__global__ void transpose_k(const short* __restrict__ hs_t, short* __restrict__ hs) {
  int g = blockIdx.x * 256 + threadIdx.x;        // 512*1024 threads
  int row = g >> 10, d = g & 1023;
#pragma unroll
  for (int i = 0; i < 3; ++i) {
    s8v v;
#pragma unroll
    for (int u = 0; u < 8; ++u)
      v[u] = hs_t[(size_t)(i * 8 + u) * (BSZ * DECD) + (size_t)row * DECD + d];
    *(s8v*)(hs + (size_t)row * KH + d * PREDT + i * 8) = v;
  }
}

// ---------------- head GEMM: C(512xN) = A(bf16) @ Bw(fp32 NxK)^T ----------------
// grid (bn, bm, z): x-period 8 = XCD count keeps each B panel on one XCD's L2.
// EPI 1: split-K partials; EPI 2: sigmoid(acc + bias1) -> out
template <int EPI>
__global__ __launch_bounds__(256, 2) void gemm2_k(
    const short* __restrict__ A, int lda, const float* __restrict__ Bw, int ldb,
    int ntiles, int kchunk, const float* __restrict__ bias1,
    float* __restrict__ Cf, int ldc) {
  __shared__ __align__(16) char sA[2][16384];
  __shared__ __align__(16) char sB[2][16384];
  int tid = threadIdx.x, lane = tid & 63, wid = tid >> 6;
  int wr = wid >> 1, wc = wid & 1, l4 = lane & 15, lg = lane >> 4;
  int bn = blockIdx.x * 128, bm = blockIdx.y * 128;
  int k0 = blockIdx.z * kchunk;
  size_t zoff = (size_t)blockIdx.z * BSZ * (size_t)ldc;
  s8v aR[4]; f4v bR[4][2];
  auto LOAD = [&](int kt) {
    int kk = k0 + kt * 64;
#pragma unroll
    for (int i = 0; i < 4; ++i) {
      int c = tid + i * 256, r = c >> 3, sl = c & 7;
      aR[i] = *(const s8v*)(A + (size_t)(bm + r) * lda + kk + sl * 8);
      const float* src = Bw + (size_t)(bn + r) * ldb + kk + sl * 8;
      bR[i][0] = *(const f4v*)src;
      bR[i][1] = *(const f4v*)(src + 4);
    }
  };
  auto WRITE = [&](int buf) {
#pragma unroll
    for (int i = 0; i < 4; ++i) {
      int c = tid + i * 256, r = c >> 3, sl = c & 7;
      *(s8v*)(sA[buf] + lds_off(r, sl * 16)) = aR[i];
      s8v v;
#pragma unroll
      for (int j = 0; j < 4; ++j) { v[j] = bf16_of(bR[i][0][j]); v[4 + j] = bf16_of(bR[i][1][j]); }
      *(s8v*)(sB[buf] + lds_off(r, sl * 16)) = v;
    }
  };
  f4v acc[4][4] = {};
  LOAD(0); WRITE(0);
  if (ntiles > 1) LOAD(1);
  __syncthreads();
  for (int kt = 0; kt < ntiles; ++kt) {
    int cur = kt & 1;
    if (kt + 1 < ntiles) WRITE(cur ^ 1);
    if (kt + 2 < ntiles) LOAD(kt + 2);
#pragma unroll
    for (int ks = 0; ks < 2; ++ks) {
      int colb = ks * 64 + lg * 16;
      s8v af[4], bf[4];
#pragma unroll
      for (int mi = 0; mi < 4; ++mi)
        af[mi] = *(const s8v*)(sA[cur] + lds_off(wr * 64 + mi * 16 + l4, colb));
#pragma unroll
      for (int ni = 0; ni < 4; ++ni)
        bf[ni] = *(const s8v*)(sB[cur] + lds_off(wc * 64 + ni * 16 + l4, colb));
#pragma unroll
      for (int mi = 0; mi < 4; ++mi)
#pragma unroll
        for (int ni = 0; ni < 4; ++ni)
          acc[mi][ni] = __builtin_amdgcn_mfma_f32_16x16x32_bf16(af[mi], bf[ni], acc[mi][ni], 0, 0, 0);
    }
    __syncthreads();
  }
#pragma unroll
  for (int mi = 0; mi < 4; ++mi)
#pragma unroll
    for (int ni = 0; ni < 4; ++ni)
#pragma unroll
      for (int j = 0; j < 4; ++j) {
        int row = bm + wr * 64 + mi * 16 + lg * 4 + j;
        int col = bn + wc * 64 + ni * 16 + l4;
        float v = acc[mi][ni][j];
        if (EPI == 1) Cf[zoff + (size_t)row * ldc + col] = v;
        else Cf[(size_t)row * ldc + col] = sigf(v + bias1[col]);
      }
}

// ---------------- head1 reduce: z1 = bf16(sigmoid(sum_{z<16} part + b_l1)) ----------------
__global__ void reduce16(const float* __restrict__ part, const float* __restrict__ b_l1,
                         short* __restrict__ z1) {
  int i4 = blockIdx.x * 256 + threadIdx.x;     // over 512*1024/4
  int base = i4 * 4;
  int n = base & (DECD - 1);
  f4v s = *(const f4v*)(b_l1 + n);
#pragma unroll
  for (int z = 0; z < 16; ++z) {
    f4v p = *(const f4v*)(part + (size_t)z * (BSZ * DECD) + base);
#pragma unroll
    for (int j = 0; j < 4; ++j) s[j] += p[j];
  }
  s4v o;
#pragma unroll
  for (int j = 0; j < 4; ++j) o[j] = bf16_of(sigf(s[j]));
  *(s4v*)(z1 + base) = o;
}

// ---------------- launch ----------------

extern "C" void kernel_launch(void* const* d_in, const int* in_sizes, int n_in,
                              void* d_out, int out_size, void* d_ws, size_t ws_size,
                              hipStream_t stream) {
  const float* enc  = (const float*)d_in[0];
  const float* oni  = (const float*)d_in[1];
  const float* ssi  = (const float*)d_in[2];
  const float* W_ih = (const float*)d_in[3];
  const float* b_ih = (const float*)d_in[4];
  const float* W_hh = (const float*)d_in[5];
  const float* b_hh = (const float*)d_in[6];
  const float* W_l1 = (const float*)d_in[7];
  const float* b_l1 = (const float*)d_in[8];
  const float* W_l2 = (const float*)d_in[9];
  const float* b_l2 = (const float*)d_in[10];
  float* out = (float*)d_out;
  (void)in_sizes; (void)n_in; (void)out_size; (void)ws_size;

  char* ws = (char*)d_ws;
  size_t off = 0;
  auto carve = [&](size_t bytes) { char* p = ws + off; off += (bytes + 255) & ~(size_t)255; return p; };
  // region A: dead after the 24 steps; part (33.55MB) aliases it for head1
  short* x_bf   = (short*)carve((size_t)BSZ * KPAD * 2);       //  2.16 MB
  short* wih_bf = (short*)carve((size_t)G4 * KPAD * 2);        // 17.30 MB
  short* whh_bf = (short*)carve((size_t)G4 * DECD * 2);        //  8.39 MB
  float* xp_p   = (float*)carve((size_t)BSZ * G4 * 4);         //  8.39 MB
  short* h0     = (short*)carve((size_t)BSZ * DECD * 2);       //  1.05 MB
  short* h1     = (short*)carve((size_t)BSZ * DECD * 2);       //  1.05 MB
  float* c_st   = (float*)carve((size_t)BSZ * DECD * 4);       //  2.10 MB
  float* part   = (float*)ws;                                  // 16*512*1024*4 = 33.55 MB (alias)
  if (off < (size_t)16 * BSZ * DECD * 4) off = (((size_t)16 * BSZ * DECD * 4) + 255) & ~(size_t)255;
  short* hs_t   = (short*)carve((size_t)PREDT * BSZ * DECD * 2); // 25.17 MB
  short* hs     = (short*)carve((size_t)BSZ * KH * 2);           // 25.17 MB
  short* z1     = (short*)carve((size_t)BSZ * DECD * 2);         //  1.05 MB

  prep_x  <<<(BSZ * KPAD) / 256, 256, 0, stream>>>(enc, oni, ssi, x_bf);
  prep_wih<<<(G4 * KPAD) / 256, 256, 0, stream>>>(W_ih, wih_bf);
  prep_whh<<<(G4 * DECD) / 256, 256, 0, stream>>>(W_hh, whh_bf);

  // x_proj (permuted col layout, biases folded in)
  xproj_k<<<256, 256, 0, stream>>>(x_bf, wih_bf, b_ih, b_hh, xp_p);

  // 24 LSTM steps
  step_k<true><<<dim3(8, 64), 256, 0, stream>>>(nullptr, whh_bf, xp_p, c_st, h0, hs_t, 0);
  for (int t = 1; t < PREDT; ++t) {
    short* hr = (t & 1) ? h0 : h1;
    short* hw = (t & 1) ? h1 : h0;
    step_k<false><<<dim3(8, 64), 256, 0, stream>>>(hr, whh_bf, xp_p, c_st, hw, hs_t, t);
  }

  // hs_t -> hs (row-major k = d*24+t)
  transpose_k<<<(BSZ * DECD) / 256, 256, 0, stream>>>(hs_t, hs);

  // head1: split-K=16 partials + reduce(sigmoid) -> z1 bf16  (grid x = bn for L2 locality)
  gemm2_k<1><<<dim3(8, 4, 16), 256, 0, stream>>>(hs, KH, W_l1, KH, 24, KH / 16, nullptr, part, DECD);
  reduce16<<<(BSZ * DECD) / 1024, 256, 0, stream>>>(part, b_l1, z1);

  // head2: out = sigmoid(z1 @ W_l2^T + b_l2)
  gemm2_k<2><<<dim3(8, 4, 1), 256, 0, stream>>>(z1, DECD, W_l2, DECD, 16, DECD, b_l2, out, DECD);
}

// Round 6
// 421.392 us; speedup vs baseline: 1.2855x; 1.2855x over previous
//
#include <hip/hip_runtime.h>
#include <hip/hip_bf16.h>

// Problem constants
#define BSZ   512
#define ENCD  2048
#define DECD  1024
#define TST   12
#define PREDT 24
#define INDIM 2061
#define KPAD  2112      // INDIM padded to multiple of 64
#define G4    4096      // 4*DEC
#define KH    24576     // DEC*PRED

typedef __attribute__((ext_vector_type(8))) short s8v;
typedef __attribute__((ext_vector_type(4))) short s4v;
typedef __attribute__((ext_vector_type(4))) float f4v;

__device__ __forceinline__ short bf16_of(float f) {
  union { float f; unsigned u; } x; x.f = f;
  unsigned r = x.u + 0x7fffu + ((x.u >> 16) & 1u);  // RNE
  return (short)(r >> 16);
}
__device__ __forceinline__ float sigf(float x) { return 1.f / (1.f + __expf(-x)); }
// tanh(x) = 1 - 2/(exp(2x)+1): no NaN for large |x|
__device__ __forceinline__ float tanh_(float x) { return 1.f - 2.f / (1.f + __expf(2.f * x)); }

// LDS swizzle for 128B rows (BK=64 bf16): XOR 3 row bits into 16B-slot index.
__device__ __forceinline__ int lds_off(int row, int colb) {
  return row * 128 + (colb ^ ((row & 7) << 4));
}
// LDS swizzle for 256B rows (BK=128 bf16): XOR 4 row bits into 16B-slot index
// (3-bit version leaves slots 8-15 unused by frag reads -> 8-way conflicts).
__device__ __forceinline__ int lds2(int row, int colb) {
  return row * 256 + (colb ^ ((row & 15) << 4));
}

// ---------------- prep kernels ----------------

__global__ void prep_x(const float* __restrict__ enc, const float* __restrict__ oni,
                       const float* __restrict__ ssi, short* __restrict__ x_bf) {
  int idx = blockIdx.x * 256 + threadIdx.x;
  if (idx >= BSZ * KPAD) return;
  int b = idx / KPAD, k = idx % KPAD;
  float v = 0.f;
  if (k < ENCD) v = enc[b * ENCD + k];
  else if (k == ENCD) v = oni[b];
  else if (k < INDIM) v = ssi[b * TST + (k - ENCD - 1)];
  x_bf[idx] = bf16_of(v);
}

// W_ih (4096 x 2061 fp32) -> permuted, padded bf16 [dblk 64][gate 4][dl 16][k 2112]
__global__ void prep_wih(const float* __restrict__ W, short* __restrict__ o) {
  int idx = blockIdx.x * 256 + threadIdx.x;      // over 4096*2112
  int rp = idx / KPAD; int k = idx - rp * KPAD;
  int dblk = rp >> 6, rem = rp & 63, g = rem >> 4, dl = rem & 15;
  int srow = g * 1024 + dblk * 16 + dl;
  float v = (k < INDIM) ? W[(size_t)srow * INDIM + k] : 0.f;
  o[idx] = bf16_of(v);
}

// W_hh (4096 x 1024 fp32) -> permuted bf16 [dblk 64][gate 4][dl 16][k 1024]
__global__ void prep_whh(const float* __restrict__ W, short* __restrict__ o) {
  int idx = blockIdx.x * 256 + threadIdx.x;      // over 4096*1024
  int rp = idx >> 10; int k = idx & 1023;
  int dblk = rp >> 6, rem = rp & 63, g = rem >> 4, dl = rem & 15;
  int srow = g * 1024 + dblk * 16 + dl;
  o[idx] = bf16_of(W[(size_t)srow * 1024 + k]);
}

// ---------------- x_proj GEMM ----------------
// xp_p[512][4096 permuted] = x(512x2112) @ wih_bf^T + b_ih + b_hh
__global__ __launch_bounds__(256, 1) void xproj_k(
    const short* __restrict__ x_bf, const short* __restrict__ wih_bf,
    const float* __restrict__ b_ih, const float* __restrict__ b_hh,
    float* __restrict__ xp_p) {
  __shared__ __align__(16) char sA[2][16384];
  __shared__ __align__(16) char sB[2][8192];
  int tid = threadIdx.x, lane = tid & 63, w = tid >> 6;
  int L = blockIdx.x;
  int bm = L >> 6, pb = (L & 7) * 8 + ((L >> 3) & 7);
  const int l4 = lane & 15, lg = lane >> 4;

  s8v aR[4], bR[2];
  auto LOAD = [&](int kt) {
    int kk = kt * 64;
#pragma unroll
    for (int i = 0; i < 4; ++i) {
      int c = tid + i * 256, r = c >> 3, sl = c & 7;
      aR[i] = *(const s8v*)(x_bf + (size_t)(bm * 128 + r) * KPAD + kk + sl * 8);
    }
#pragma unroll
    for (int i = 0; i < 2; ++i) {
      int c = tid + i * 256, r = c >> 3, sl = c & 7;
      bR[i] = *(const s8v*)(wih_bf + (size_t)(pb * 64 + r) * KPAD + kk + sl * 8);
    }
  };
  auto WRITE = [&](int buf) {
#pragma unroll
    for (int i = 0; i < 4; ++i) {
      int c = tid + i * 256, r = c >> 3, sl = c & 7;
      *(s8v*)(sA[buf] + lds_off(r, sl * 16)) = aR[i];
    }
#pragma unroll
    for (int i = 0; i < 2; ++i) {
      int c = tid + i * 256, r = c >> 3, sl = c & 7;
      *(s8v*)(sB[buf] + lds_off(r, sl * 16)) = bR[i];
    }
  };

  f4v acc[2][4] = {};
  LOAD(0); WRITE(0); LOAD(1);
  __syncthreads();
  for (int kt = 0; kt < 33; ++kt) {
    int cur = kt & 1;
    if (kt < 32) WRITE(cur ^ 1);
    if (kt < 31) LOAD(kt + 2);
#pragma unroll
    for (int ks = 0; ks < 2; ++ks) {
      int colb = ks * 64 + lg * 16;
      s8v af[2], bf[4];
#pragma unroll
      for (int mi = 0; mi < 2; ++mi)
        af[mi] = *(const s8v*)(sA[cur] + lds_off(w * 32 + mi * 16 + l4, colb));
#pragma unroll
      for (int ni = 0; ni < 4; ++ni)
        bf[ni] = *(const s8v*)(sB[cur] + lds_off(ni * 16 + l4, colb));
#pragma unroll
      for (int mi = 0; mi < 2; ++mi)
#pragma unroll
        for (int ni = 0; ni < 4; ++ni)
          acc[mi][ni] = __builtin_amdgcn_mfma_f32_16x16x32_bf16(af[mi], bf[ni], acc[mi][ni], 0, 0, 0);
    }
    __syncthreads();
  }
#pragma unroll
  for (int ni = 0; ni < 4; ++ni) {
    int src = ni * 1024 + pb * 16 + l4;
    float bv = b_ih[src] + b_hh[src];
#pragma unroll
    for (int mi = 0; mi < 2; ++mi)
#pragma unroll
      for (int j = 0; j < 4; ++j) {
        int row = bm * 128 + w * 32 + mi * 16 + lg * 4 + j;
        xp_p[(size_t)row * G4 + pb * 64 + ni * 16 + l4] = acc[mi][ni][j] + bv;
      }
  }
}

// ---------------- LSTM step v3 (one launch per t) ----------------
// grid (64 cp, 8 bm): id%8 = cp%8 -> each W_hh panel pinned to one XCD's L2.
// block 256 = 4 waves; wave = 16 batch rows x 64 gate-cols (4 gates x 16 d).
// K = 1024 in 8 kt of BK=128 (8 barrier phases). A per-wave LDS strip, B shared.
// 2-deep register prefetch; xp/c prefetched at top; cell consumes acc directly.
template <bool FIRST>
__global__ __launch_bounds__(256, 2) void step_k(
    const short* __restrict__ h_in, const short* __restrict__ whh_bf,
    const float* __restrict__ xp_p, float* __restrict__ c_st,
    short* __restrict__ h_out, short* __restrict__ hs_t, int tstep) {
  __shared__ __align__(16) char sB[2][16384];    // 64 gate-rows x 128 K
  __shared__ __align__(16) char sA[4][2][4096];  // per-wave 16 rows x 128 K
  int tid = threadIdx.x, lane = tid & 63, w = tid >> 6;
  int cp = blockIdx.x, bm = blockIdx.y;
  const int l4 = lane & 15, lg = lane >> 4;
  const int d = cp * 16 + l4;

  // prefetch xp (biases folded) and c for the fused cell
  float xg[4][4], cpre[4];
#pragma unroll
  for (int j = 0; j < 4; ++j) {
    int row = bm * 64 + w * 16 + lg * 4 + j;
    size_t xb = (size_t)row * G4 + cp * 64 + l4;
    xg[j][0] = xp_p[xb];
    xg[j][1] = xp_p[xb + 16];
    xg[j][2] = xp_p[xb + 32];
    xg[j][3] = xp_p[xb + 48];
    cpre[j] = FIRST ? 0.f : c_st[(size_t)row * DECD + d];
  }

  f4v acc[4] = {};   // ni = gate

  if (!FIRST) {
    const short* bbase = whh_bf + (size_t)cp * 64 * DECD;
    const short* abase = h_in + (size_t)(bm * 64 + w * 16) * DECD;
    s8v aR[4], bR[4];
    auto LOAD = [&](int kt) {
      int kk = kt * 128;
#pragma unroll
      for (int i = 0; i < 4; ++i) {
        int c = lane + i * 64, r = c >> 4, sl = c & 15;     // 256 chunks / wave
        aR[i] = *(const s8v*)(abase + (size_t)r * DECD + kk + sl * 8);
      }
#pragma unroll
      for (int i = 0; i < 4; ++i) {
        int c = tid + i * 256, r = c >> 4, sl = c & 15;     // 1024 chunks / block
        bR[i] = *(const s8v*)(bbase + (size_t)r * DECD + kk + sl * 8);
      }
    };
    auto WRITE = [&](int buf) {
#pragma unroll
      for (int i = 0; i < 4; ++i) {
        int c = lane + i * 64, r = c >> 4, sl = c & 15;
        *(s8v*)(sA[w][buf] + lds2(r, sl * 16)) = aR[i];
      }
#pragma unroll
      for (int i = 0; i < 4; ++i) {
        int c = tid + i * 256, r = c >> 4, sl = c & 15;
        *(s8v*)(sB[buf] + lds2(r, sl * 16)) = bR[i];
      }
    };
    LOAD(0); WRITE(0); LOAD(1);
    __syncthreads();
    for (int kt = 0; kt < 8; ++kt) {
      int cur = kt & 1;
      if (kt < 7) WRITE(cur ^ 1);      // regs hold tile kt+1
      if (kt < 6) LOAD(kt + 2);
#pragma unroll
      for (int ks = 0; ks < 4; ++ks) {
        int colb = ks * 64 + lg * 16;
        s8v af = *(const s8v*)(sA[w][cur] + lds2(l4, colb));
        s8v bf[4];
#pragma unroll
        for (int ni = 0; ni < 4; ++ni)
          bf[ni] = *(const s8v*)(sB[cur] + lds2(ni * 16 + l4, colb));
#pragma unroll
        for (int ni = 0; ni < 4; ++ni)
          acc[ni] = __builtin_amdgcn_mfma_f32_16x16x32_bf16(af, bf[ni], acc[ni], 0, 0, 0);
      }
      __syncthreads();
    }
  }

  // fused cell: thread owns rows (w*16 + lg*4 + j) x d, all 4 gates in acc[ni][j]
#pragma unroll
  for (int j = 0; j < 4; ++j) {
    int row = bm * 64 + w * 16 + lg * 4 + j;
    float gi = xg[j][0] + acc[0][j];
    float gf = xg[j][1] + acc[1][j];
    float gg = xg[j][2] + acc[2][j];
    float go = xg[j][3] + acc[3][j];
    float cn = sigf(gf) * cpre[j] + sigf(gi) * tanh_(gg);
    float h = sigf(go) * tanh_(cn);
    size_t cd = (size_t)row * DECD + d;
    c_st[cd] = cn;
    short hb = bf16_of(h);
    if (tstep < 23) h_out[cd] = hb;
    hs_t[(size_t)tstep * (BSZ * DECD) + cd] = hb;
  }
}

// ---------------- transpose: hs_t[t][row][d] -> hs[row][d*24+t] ----------------
__global__ void transpose_k(const short* __restrict__ hs_t, short* __restrict__ hs) {
  int g = blockIdx.x * 256 + threadIdx.x;        // 512*1024 threads
  int row = g >> 10, d = g & 1023;
#pragma unroll
  for (int i = 0; i < 3; ++i) {
    s8v v;
#pragma unroll
    for (int u = 0; u < 8; ++u)
      v[u] = hs_t[(size_t)(i * 8 + u) * (BSZ * DECD) + (size_t)row * DECD + d];
    *(s8v*)(hs + (size_t)row * KH + d * PREDT + i * 8) = v;
  }
}

// ---------------- head GEMM: C(512xN) = A(bf16) @ Bw(fp32 NxK)^T ----------------
// grid (bn, bm, z): x-period 8 = XCD count keeps each B panel on one XCD's L2.
// EPI 1: split-K partials; EPI 2: sigmoid(acc + bias1) -> out
template <int EPI>
__global__ __launch_bounds__(256, 2) void gemm2_k(
    const short* __restrict__ A, int lda, const float* __restrict__ Bw, int ldb,
    int ntiles, int kchunk, const float* __restrict__ bias1,
    float* __restrict__ Cf, int ldc) {
  __shared__ __align__(16) char sA[2][16384];
  __shared__ __align__(16) char sB[2][16384];
  int tid = threadIdx.x, lane = tid & 63, wid = tid >> 6;
  int wr = wid >> 1, wc = wid & 1, l4 = lane & 15, lg = lane >> 4;
  int bn = blockIdx.x * 128, bm = blockIdx.y * 128;
  int k0 = blockIdx.z * kchunk;
  size_t zoff = (size_t)blockIdx.z * BSZ * (size_t)ldc;
  s8v aR[4]; f4v bR[4][2];
  auto LOAD = [&](int kt) {
    int kk = k0 + kt * 64;
#pragma unroll
    for (int i = 0; i < 4; ++i) {
      int c = tid + i * 256, r = c >> 3, sl = c & 7;
      aR[i] = *(const s8v*)(A + (size_t)(bm + r) * lda + kk + sl * 8);
      const float* src = Bw + (size_t)(bn + r) * ldb + kk + sl * 8;
      bR[i][0] = *(const f4v*)src;
      bR[i][1] = *(const f4v*)(src + 4);
    }
  };
  auto WRITE = [&](int buf) {
#pragma unroll
    for (int i = 0; i < 4; ++i) {
      int c = tid + i * 256, r = c >> 3, sl = c & 7;
      *(s8v*)(sA[buf] + lds_off(r, sl * 16)) = aR[i];
      s8v v;
#pragma unroll
      for (int j = 0; j < 4; ++j) { v[j] = bf16_of(bR[i][0][j]); v[4 + j] = bf16_of(bR[i][1][j]); }
      *(s8v*)(sB[buf] + lds_off(r, sl * 16)) = v;
    }
  };
  f4v acc[4][4] = {};
  LOAD(0); WRITE(0);
  if (ntiles > 1) LOAD(1);
  __syncthreads();
  for (int kt = 0; kt < ntiles; ++kt) {
    int cur = kt & 1;
    if (kt + 1 < ntiles) WRITE(cur ^ 1);
    if (kt + 2 < ntiles) LOAD(kt + 2);
#pragma unroll
    for (int ks = 0; ks < 2; ++ks) {
      int colb = ks * 64 + lg * 16;
      s8v af[4], bf[4];
#pragma unroll
      for (int mi = 0; mi < 4; ++mi)
        af[mi] = *(const s8v*)(sA[cur] + lds_off(wr * 64 + mi * 16 + l4, colb));
#pragma unroll
      for (int ni = 0; ni < 4; ++ni)
        bf[ni] = *(const s8v*)(sB[cur] + lds_off(wc * 64 + ni * 16 + l4, colb));
#pragma unroll
      for (int mi = 0; mi < 4; ++mi)
#pragma unroll
        for (int ni = 0; ni < 4; ++ni)
          acc[mi][ni] = __builtin_amdgcn_mfma_f32_16x16x32_bf16(af[mi], bf[ni], acc[mi][ni], 0, 0, 0);
    }
    __syncthreads();
  }
#pragma unroll
  for (int mi = 0; mi < 4; ++mi)
#pragma unroll
    for (int ni = 0; ni < 4; ++ni)
#pragma unroll
      for (int j = 0; j < 4; ++j) {
        int row = bm + wr * 64 + mi * 16 + lg * 4 + j;
        int col = bn + wc * 64 + ni * 16 + l4;
        float v = acc[mi][ni][j];
        if (EPI == 1) Cf[zoff + (size_t)row * ldc + col] = v;
        else Cf[(size_t)row * ldc + col] = sigf(v + bias1[col]);
      }
}

// ---------------- head1 reduce: z1 = bf16(sigmoid(sum_{z<16} part + b_l1)) ----------------
__global__ void reduce16(const float* __restrict__ part, const float* __restrict__ b_l1,
                         short* __restrict__ z1) {
  int i4 = blockIdx.x * 256 + threadIdx.x;     // over 512*1024/4
  int base = i4 * 4;
  int n = base & (DECD - 1);
  f4v s = *(const f4v*)(b_l1 + n);
#pragma unroll
  for (int z = 0; z < 16; ++z) {
    f4v p = *(const f4v*)(part + (size_t)z * (BSZ * DECD) + base);
#pragma unroll
    for (int j = 0; j < 4; ++j) s[j] += p[j];
  }
  s4v o;
#pragma unroll
  for (int j = 0; j < 4; ++j) o[j] = bf16_of(sigf(s[j]));
  *(s4v*)(z1 + base) = o;
}

// ---------------- launch ----------------

extern "C" void kernel_launch(void* const* d_in, const int* in_sizes, int n_in,
                              void* d_out, int out_size, void* d_ws, size_t ws_size,
                              hipStream_t stream) {
  const float* enc  = (const float*)d_in[0];
  const float* oni  = (const float*)d_in[1];
  const float* ssi  = (const float*)d_in[2];
  const float* W_ih = (const float*)d_in[3];
  const float* b_ih = (const float*)d_in[4];
  const float* W_hh = (const float*)d_in[5];
  const float* b_hh = (const float*)d_in[6];
  const float* W_l1 = (const float*)d_in[7];
  const float* b_l1 = (const float*)d_in[8];
  const float* W_l2 = (const float*)d_in[9];
  const float* b_l2 = (const float*)d_in[10];
  float* out = (float*)d_out;
  (void)in_sizes; (void)n_in; (void)out_size; (void)ws_size;

  char* ws = (char*)d_ws;
  size_t off = 0;
  auto carve = [&](size_t bytes) { char* p = ws + off; off += (bytes + 255) & ~(size_t)255; return p; };
  // region A: dead after the 24 steps; part (33.55MB) aliases it for head1
  short* x_bf   = (short*)carve((size_t)BSZ * KPAD * 2);       //  2.16 MB
  short* wih_bf = (short*)carve((size_t)G4 * KPAD * 2);        // 17.30 MB
  short* whh_bf = (short*)carve((size_t)G4 * DECD * 2);        //  8.39 MB
  float* xp_p   = (float*)carve((size_t)BSZ * G4 * 4);         //  8.39 MB
  short* h0     = (short*)carve((size_t)BSZ * DECD * 2);       //  1.05 MB
  short* h1     = (short*)carve((size_t)BSZ * DECD * 2);       //  1.05 MB
  float* c_st   = (float*)carve((size_t)BSZ * DECD * 4);       //  2.10 MB
  float* part   = (float*)ws;                                  // 16*512*1024*4 = 33.55 MB (alias)
  if (off < (size_t)16 * BSZ * DECD * 4) off = (((size_t)16 * BSZ * DECD * 4) + 255) & ~(size_t)255;
  short* hs_t   = (short*)carve((size_t)PREDT * BSZ * DECD * 2); // 25.17 MB
  short* hs     = (short*)carve((size_t)BSZ * KH * 2);           // 25.17 MB
  short* z1     = (short*)carve((size_t)BSZ * DECD * 2);         //  1.05 MB

  prep_x  <<<(BSZ * KPAD) / 256, 256, 0, stream>>>(enc, oni, ssi, x_bf);
  prep_wih<<<(G4 * KPAD) / 256, 256, 0, stream>>>(W_ih, wih_bf);
  prep_whh<<<(G4 * DECD) / 256, 256, 0, stream>>>(W_hh, whh_bf);

  // x_proj (permuted col layout, biases folded in)
  xproj_k<<<256, 256, 0, stream>>>(x_bf, wih_bf, b_ih, b_hh, xp_p);

  // 24 LSTM steps (grid x = cp so each W_hh panel stays on one XCD's L2)
  step_k<true><<<dim3(64, 8), 256, 0, stream>>>(nullptr, whh_bf, xp_p, c_st, h0, hs_t, 0);
  for (int t = 1; t < PREDT; ++t) {
    short* hr = (t & 1) ? h0 : h1;
    short* hw = (t & 1) ? h1 : h0;
    step_k<false><<<dim3(64, 8), 256, 0, stream>>>(hr, whh_bf, xp_p, c_st, hw, hs_t, t);
  }

  // hs_t -> hs (row-major k = d*24+t)
  transpose_k<<<(BSZ * DECD) / 256, 256, 0, stream>>>(hs_t, hs);

  // head1: split-K=16 partials + reduce(sigmoid) -> z1 bf16  (grid x = bn for L2 locality)
  gemm2_k<1><<<dim3(8, 4, 16), 256, 0, stream>>>(hs, KH, W_l1, KH, 24, KH / 16, nullptr, part, DECD);
  reduce16<<<(BSZ * DECD) / 1024, 256, 0, stream>>>(part, b_l1, z1);

  // head2: out = sigmoid(z1 @ W_l2^T + b_l2)
  gemm2_k<2><<<dim3(8, 4, 1), 256, 0, stream>>>(z1, DECD, W_l2, DECD, 16, DECD, b_l2, out, DECD);
}

// Round 7
// 411.953 us; speedup vs baseline: 1.3150x; 1.0229x over previous
//
#include <hip/hip_runtime.h>
#include <hip/hip_bf16.h>

// Problem constants
#define BSZ   512
#define ENCD  2048
#define DECD  1024
#define TST   12
#define PREDT 24
#define INDIM 2061
#define KPAD  2112      // INDIM padded to multiple of 64
#define G4    4096      // 4*DEC
#define KH    24576     // DEC*PRED

typedef __attribute__((ext_vector_type(8))) short s8v;
typedef __attribute__((ext_vector_type(4))) short s4v;
typedef __attribute__((ext_vector_type(4))) float f4v;

__device__ __forceinline__ short bf16_of(float f) {
  union { float f; unsigned u; } x; x.f = f;
  unsigned r = x.u + 0x7fffu + ((x.u >> 16) & 1u);  // RNE
  return (short)(r >> 16);
}
__device__ __forceinline__ float sigf(float x) { return 1.f / (1.f + __expf(-x)); }
// tanh(x) = 1 - 2/(exp(2x)+1): no NaN for large |x|
__device__ __forceinline__ float tanh_(float x) { return 1.f - 2.f / (1.f + __expf(2.f * x)); }

// LDS swizzle for 128B rows (BK=64 bf16): XOR 3 row bits into 16B-slot index.
__device__ __forceinline__ int lds_off(int row, int colb) {
  return row * 128 + (colb ^ ((row & 7) << 4));
}

// ---------------- prep kernels ----------------

__global__ void prep_x(const float* __restrict__ enc, const float* __restrict__ oni,
                       const float* __restrict__ ssi, short* __restrict__ x_bf) {
  int idx = blockIdx.x * 256 + threadIdx.x;
  if (idx >= BSZ * KPAD) return;
  int b = idx / KPAD, k = idx % KPAD;
  float v = 0.f;
  if (k < ENCD) v = enc[b * ENCD + k];
  else if (k == ENCD) v = oni[b];
  else if (k < INDIM) v = ssi[b * TST + (k - ENCD - 1)];
  x_bf[idx] = bf16_of(v);
}

// W_ih (4096 x 2061 fp32) -> permuted, padded bf16 [dblk 64][gate 4][dl 16][k 2112]
__global__ void prep_wih(const float* __restrict__ W, short* __restrict__ o) {
  int idx = blockIdx.x * 256 + threadIdx.x;      // over 4096*2112
  int rp = idx / KPAD; int k = idx - rp * KPAD;
  int dblk = rp >> 6, rem = rp & 63, g = rem >> 4, dl = rem & 15;
  int srow = g * 1024 + dblk * 16 + dl;
  float v = (k < INDIM) ? W[(size_t)srow * INDIM + k] : 0.f;
  o[idx] = bf16_of(v);
}

// W_hh (4096 x 1024 fp32) -> permuted bf16 [dblk 64][gate 4][dl 16][k 1024]
__global__ void prep_whh(const float* __restrict__ W, short* __restrict__ o) {
  int idx = blockIdx.x * 256 + threadIdx.x;      // over 4096*1024
  int rp = idx >> 10; int k = idx & 1023;
  int dblk = rp >> 6, rem = rp & 63, g = rem >> 4, dl = rem & 15;
  int srow = g * 1024 + dblk * 16 + dl;
  o[idx] = bf16_of(W[(size_t)srow * 1024 + k]);
}

// ---------------- x_proj GEMM ----------------
// xp_p[512][4096 permuted] = x(512x2112) @ wih_bf^T + b_ih + b_hh
__global__ __launch_bounds__(256, 1) void xproj_k(
    const short* __restrict__ x_bf, const short* __restrict__ wih_bf,
    const float* __restrict__ b_ih, const float* __restrict__ b_hh,
    float* __restrict__ xp_p) {
  __shared__ __align__(16) char sA[2][16384];
  __shared__ __align__(16) char sB[2][8192];
  int tid = threadIdx.x, lane = tid & 63, w = tid >> 6;
  int L = blockIdx.x;
  int bm = L >> 6, pb = (L & 7) * 8 + ((L >> 3) & 7);
  const int l4 = lane & 15, lg = lane >> 4;

  s8v aR[4], bR[2];
  auto LOAD = [&](int kt) {
    int kk = kt * 64;
#pragma unroll
    for (int i = 0; i < 4; ++i) {
      int c = tid + i * 256, r = c >> 3, sl = c & 7;
      aR[i] = *(const s8v*)(x_bf + (size_t)(bm * 128 + r) * KPAD + kk + sl * 8);
    }
#pragma unroll
    for (int i = 0; i < 2; ++i) {
      int c = tid + i * 256, r = c >> 3, sl = c & 7;
      bR[i] = *(const s8v*)(wih_bf + (size_t)(pb * 64 + r) * KPAD + kk + sl * 8);
    }
  };
  auto WRITE = [&](int buf) {
#pragma unroll
    for (int i = 0; i < 4; ++i) {
      int c = tid + i * 256, r = c >> 3, sl = c & 7;
      *(s8v*)(sA[buf] + lds_off(r, sl * 16)) = aR[i];
    }
#pragma unroll
    for (int i = 0; i < 2; ++i) {
      int c = tid + i * 256, r = c >> 3, sl = c & 7;
      *(s8v*)(sB[buf] + lds_off(r, sl * 16)) = bR[i];
    }
  };

  f4v acc[2][4] = {};
  LOAD(0); WRITE(0); LOAD(1);
  __syncthreads();
  for (int kt = 0; kt < 33; ++kt) {
    int cur = kt & 1;
    if (kt < 32) WRITE(cur ^ 1);
    if (kt < 31) LOAD(kt + 2);
#pragma unroll
    for (int ks = 0; ks < 2; ++ks) {
      int colb = ks * 64 + lg * 16;
      s8v af[2], bf[4];
#pragma unroll
      for (int mi = 0; mi < 2; ++mi)
        af[mi] = *(const s8v*)(sA[cur] + lds_off(w * 32 + mi * 16 + l4, colb));
#pragma unroll
      for (int ni = 0; ni < 4; ++ni)
        bf[ni] = *(const s8v*)(sB[cur] + lds_off(ni * 16 + l4, colb));
#pragma unroll
      for (int mi = 0; mi < 2; ++mi)
#pragma unroll
        for (int ni = 0; ni < 4; ++ni)
          acc[mi][ni] = __builtin_amdgcn_mfma_f32_16x16x32_bf16(af[mi], bf[ni], acc[mi][ni], 0, 0, 0);
    }
    __syncthreads();
  }
#pragma unroll
  for (int ni = 0; ni < 4; ++ni) {
    int src = ni * 1024 + pb * 16 + l4;
    float bv = b_ih[src] + b_hh[src];
#pragma unroll
    for (int mi = 0; mi < 2; ++mi)
#pragma unroll
      for (int j = 0; j < 4; ++j) {
        int row = bm * 128 + w * 32 + mi * 16 + lg * 4 + j;
        xp_p[(size_t)row * G4 + pb * 64 + ni * 16 + l4] = acc[mi][ni][j] + bv;
      }
  }
}

// ---------------- LSTM step v4 (one launch per t) ----------------
// grid (64 cp, 4 bm): id%8 = cp%8 -> W_hh panel pinned per-XCD L2.
// block 256 = 4 waves; wave = 32 batch rows (mi 2x16) x 64 gate-cols (ni=gate).
// Doubling rows/wave cuts LDS ops/CU/step 1792 -> 1152 (B-frag reuse over 2 mi).
// BK=64, 16 phases, per-wave A strip + shared B, 2-deep register prefetch.
template <bool FIRST>
__global__ __launch_bounds__(256, 2) void step_k(
    const short* __restrict__ h_in, const short* __restrict__ whh_bf,
    const float* __restrict__ xp_p, float* __restrict__ c_st,
    short* __restrict__ h_out, short* __restrict__ hs_t, int tstep) {
  __shared__ __align__(16) char sB[2][8192];      // 64 gate-rows x 64 k
  __shared__ __align__(16) char sA[4][2][4096];   // per-wave 32 rows x 64 k
  int tid = threadIdx.x, lane = tid & 63, w = tid >> 6;
  int cp = blockIdx.x, bm = blockIdx.y;
  const int l4 = lane & 15, lg = lane >> 4;
  const int d = cp * 16 + l4;

  // prefetch xp (biases folded) and c for the fused cell
  float xg[2][4][4], cpre[2][4];
#pragma unroll
  for (int mi = 0; mi < 2; ++mi)
#pragma unroll
    for (int j = 0; j < 4; ++j) {
      int row = bm * 128 + w * 32 + mi * 16 + lg * 4 + j;
      size_t xb = (size_t)row * G4 + cp * 64 + l4;
      xg[mi][j][0] = xp_p[xb];
      xg[mi][j][1] = xp_p[xb + 16];
      xg[mi][j][2] = xp_p[xb + 32];
      xg[mi][j][3] = xp_p[xb + 48];
      cpre[mi][j] = FIRST ? 0.f : c_st[(size_t)row * DECD + d];
    }

  f4v acc[2][4] = {};   // [mi][gate]

  if (!FIRST) {
    const short* bbase = whh_bf + (size_t)cp * 64 * DECD;
    const short* abase = h_in + (size_t)(bm * 128 + w * 32) * DECD;
    s8v aR[4], bR[2];
    auto LOAD = [&](int kt) {
      int kk = kt * 64;
#pragma unroll
      for (int i = 0; i < 4; ++i) {               // 32 rows x 64k: 256 chunks/wave
        int c = lane + i * 64, r = c >> 3, sl = c & 7;
        aR[i] = *(const s8v*)(abase + (size_t)r * DECD + kk + sl * 8);
      }
#pragma unroll
      for (int i = 0; i < 2; ++i) {               // 64 rows x 64k: 512 chunks/block
        int c = tid + i * 256, r = c >> 3, sl = c & 7;
        bR[i] = *(const s8v*)(bbase + (size_t)r * DECD + kk + sl * 8);
      }
    };
    auto WRITE = [&](int buf) {
#pragma unroll
      for (int i = 0; i < 4; ++i) {
        int c = lane + i * 64, r = c >> 3, sl = c & 7;
        *(s8v*)(sA[w][buf] + lds_off(r, sl * 16)) = aR[i];
      }
#pragma unroll
      for (int i = 0; i < 2; ++i) {
        int c = tid + i * 256, r = c >> 3, sl = c & 7;
        *(s8v*)(sB[buf] + lds_off(r, sl * 16)) = bR[i];
      }
    };
    LOAD(0); WRITE(0); LOAD(1);
    __syncthreads();
    for (int kt = 0; kt < 16; ++kt) {
      int cur = kt & 1;
      if (kt < 15) WRITE(cur ^ 1);      // regs hold tile kt+1
      if (kt < 14) LOAD(kt + 2);
#pragma unroll
      for (int ks = 0; ks < 2; ++ks) {
        int colb = ks * 64 + lg * 16;
        s8v af[2], bf[4];
#pragma unroll
        for (int mi = 0; mi < 2; ++mi)
          af[mi] = *(const s8v*)(sA[w][cur] + lds_off(mi * 16 + l4, colb));
#pragma unroll
        for (int ni = 0; ni < 4; ++ni)
          bf[ni] = *(const s8v*)(sB[cur] + lds_off(ni * 16 + l4, colb));
#pragma unroll
        for (int mi = 0; mi < 2; ++mi)
#pragma unroll
          for (int ni = 0; ni < 4; ++ni)
            acc[mi][ni] = __builtin_amdgcn_mfma_f32_16x16x32_bf16(af[mi], bf[ni], acc[mi][ni], 0, 0, 0);
      }
      __syncthreads();
    }
  }

  // fused cell: thread owns rows (w*32 + mi*16 + lg*4 + j) x d, 4 gates in acc[mi][ni][j]
#pragma unroll
  for (int mi = 0; mi < 2; ++mi)
#pragma unroll
    for (int j = 0; j < 4; ++j) {
      int row = bm * 128 + w * 32 + mi * 16 + lg * 4 + j;
      float gi = xg[mi][j][0] + acc[mi][0][j];
      float gf = xg[mi][j][1] + acc[mi][1][j];
      float gg = xg[mi][j][2] + acc[mi][2][j];
      float go = xg[mi][j][3] + acc[mi][3][j];
      float cn = sigf(gf) * cpre[mi][j] + sigf(gi) * tanh_(gg);
      float h = sigf(go) * tanh_(cn);
      size_t cd = (size_t)row * DECD + d;
      c_st[cd] = cn;
      short hb = bf16_of(h);
      if (tstep < 23) h_out[cd] = hb;
      hs_t[(size_t)tstep * (BSZ * DECD) + cd] = hb;
    }
}

// ---------------- transpose: hs_t[t][row][d] -> hs[row][d*24+t] ----------------
__global__ void transpose_k(const short* __restrict__ hs_t, short* __restrict__ hs) {
  int g = blockIdx.x * 256 + threadIdx.x;        // 512*1024 threads
  int row = g >> 10, d = g & 1023;
#pragma unroll
  for (int i = 0; i < 3; ++i) {
    s8v v;
#pragma unroll
    for (int u = 0; u < 8; ++u)
      v[u] = hs_t[(size_t)(i * 8 + u) * (BSZ * DECD) + (size_t)row * DECD + d];
    *(s8v*)(hs + (size_t)row * KH + d * PREDT + i * 8) = v;
  }
}

// ---------------- head GEMM: C(512xN) = A(bf16) @ Bw(fp32 NxK)^T ----------------
// grid (bn, bm, z): x-period 8 = XCD count keeps each B panel on one XCD's L2.
// EPI 1: split-K partials; EPI 2: sigmoid(acc + bias1) -> out
template <int EPI>
__global__ __launch_bounds__(256, 2) void gemm2_k(
    const short* __restrict__ A, int lda, const float* __restrict__ Bw, int ldb,
    int ntiles, int kchunk, const float* __restrict__ bias1,
    float* __restrict__ Cf, int ldc) {
  __shared__ __align__(16) char sA[2][16384];
  __shared__ __align__(16) char sB[2][16384];
  int tid = threadIdx.x, lane = tid & 63, wid = tid >> 6;
  int wr = wid >> 1, wc = wid & 1, l4 = lane & 15, lg = lane >> 4;
  int bn = blockIdx.x * 128, bm = blockIdx.y * 128;
  int k0 = blockIdx.z * kchunk;
  size_t zoff = (size_t)blockIdx.z * BSZ * (size_t)ldc;
  s8v aR[4]; f4v bR[4][2];
  auto LOAD = [&](int kt) {
    int kk = k0 + kt * 64;
#pragma unroll
    for (int i = 0; i < 4; ++i) {
      int c = tid + i * 256, r = c >> 3, sl = c & 7;
      aR[i] = *(const s8v*)(A + (size_t)(bm + r) * lda + kk + sl * 8);
      const float* src = Bw + (size_t)(bn + r) * ldb + kk + sl * 8;
      bR[i][0] = *(const f4v*)src;
      bR[i][1] = *(const f4v*)(src + 4);
    }
  };
  auto WRITE = [&](int buf) {
#pragma unroll
    for (int i = 0; i < 4; ++i) {
      int c = tid + i * 256, r = c >> 3, sl = c & 7;
      *(s8v*)(sA[buf] + lds_off(r, sl * 16)) = aR[i];
      s8v v;
#pragma unroll
      for (int j = 0; j < 4; ++j) { v[j] = bf16_of(bR[i][0][j]); v[4 + j] = bf16_of(bR[i][1][j]); }
      *(s8v*)(sB[buf] + lds_off(r, sl * 16)) = v;
    }
  };
  f4v acc[4][4] = {};
  LOAD(0); WRITE(0);
  if (ntiles > 1) LOAD(1);
  __syncthreads();
  for (int kt = 0; kt < ntiles; ++kt) {
    int cur = kt & 1;
    if (kt + 1 < ntiles) WRITE(cur ^ 1);
    if (kt + 2 < ntiles) LOAD(kt + 2);
#pragma unroll
    for (int ks = 0; ks < 2; ++ks) {
      int colb = ks * 64 + lg * 16;
      s8v af[4], bf[4];
#pragma unroll
      for (int mi = 0; mi < 4; ++mi)
        af[mi] = *(const s8v*)(sA[cur] + lds_off(wr * 64 + mi * 16 + l4, colb));
#pragma unroll
      for (int ni = 0; ni < 4; ++ni)
        bf[ni] = *(const s8v*)(sB[cur] + lds_off(wc * 64 + ni * 16 + l4, colb));
#pragma unroll
      for (int mi = 0; mi < 4; ++mi)
#pragma unroll
        for (int ni = 0; ni < 4; ++ni)
          acc[mi][ni] = __builtin_amdgcn_mfma_f32_16x16x32_bf16(af[mi], bf[ni], acc[mi][ni], 0, 0, 0);
    }
    __syncthreads();
  }
#pragma unroll
  for (int mi = 0; mi < 4; ++mi)
#pragma unroll
    for (int ni = 0; ni < 4; ++ni)
#pragma unroll
      for (int j = 0; j < 4; ++j) {
        int row = bm + wr * 64 + mi * 16 + lg * 4 + j;
        int col = bn + wc * 64 + ni * 16 + l4;
        float v = acc[mi][ni][j];
        if (EPI == 1) Cf[zoff + (size_t)row * ldc + col] = v;
        else Cf[(size_t)row * ldc + col] = sigf(v + bias1[col]);
      }
}

// ---------------- head1 reduce: z1 = bf16(sigmoid(sum_{z<16} part + b_l1)) ----------------
__global__ void reduce16(const float* __restrict__ part, const float* __restrict__ b_l1,
                         short* __restrict__ z1) {
  int i4 = blockIdx.x * 256 + threadIdx.x;     // over 512*1024/4
  int base = i4 * 4;
  int n = base & (DECD - 1);
  f4v s = *(const f4v*)(b_l1 + n);
#pragma unroll
  for (int z = 0; z < 16; ++z) {
    f4v p = *(const f4v*)(part + (size_t)z * (BSZ * DECD) + base);
#pragma unroll
    for (int j = 0; j < 4; ++j) s[j] += p[j];
  }
  s4v o;
#pragma unroll
  for (int j = 0; j < 4; ++j) o[j] = bf16_of(sigf(s[j]));
  *(s4v*)(z1 + base) = o;
}

// ---------------- launch ----------------

extern "C" void kernel_launch(void* const* d_in, const int* in_sizes, int n_in,
                              void* d_out, int out_size, void* d_ws, size_t ws_size,
                              hipStream_t stream) {
  const float* enc  = (const float*)d_in[0];
  const float* oni  = (const float*)d_in[1];
  const float* ssi  = (const float*)d_in[2];
  const float* W_ih = (const float*)d_in[3];
  const float* b_ih = (const float*)d_in[4];
  const float* W_hh = (const float*)d_in[5];
  const float* b_hh = (const float*)d_in[6];
  const float* W_l1 = (const float*)d_in[7];
  const float* b_l1 = (const float*)d_in[8];
  const float* W_l2 = (const float*)d_in[9];
  const float* b_l2 = (const float*)d_in[10];
  float* out = (float*)d_out;
  (void)in_sizes; (void)n_in; (void)out_size; (void)ws_size;

  char* ws = (char*)d_ws;
  size_t off = 0;
  auto carve = [&](size_t bytes) { char* p = ws + off; off += (bytes + 255) & ~(size_t)255; return p; };
  // region A: dead after the 24 steps; part (33.55MB) aliases it for head1
  short* x_bf   = (short*)carve((size_t)BSZ * KPAD * 2);       //  2.16 MB
  short* wih_bf = (short*)carve((size_t)G4 * KPAD * 2);        // 17.30 MB
  short* whh_bf = (short*)carve((size_t)G4 * DECD * 2);        //  8.39 MB
  float* xp_p   = (float*)carve((size_t)BSZ * G4 * 4);         //  8.39 MB
  short* h0     = (short*)carve((size_t)BSZ * DECD * 2);       //  1.05 MB
  short* h1     = (short*)carve((size_t)BSZ * DECD * 2);       //  1.05 MB
  float* c_st   = (float*)carve((size_t)BSZ * DECD * 4);       //  2.10 MB
  float* part   = (float*)ws;                                  // 16*512*1024*4 = 33.55 MB (alias)
  if (off < (size_t)16 * BSZ * DECD * 4) off = (((size_t)16 * BSZ * DECD * 4) + 255) & ~(size_t)255;
  short* hs_t   = (short*)carve((size_t)PREDT * BSZ * DECD * 2); // 25.17 MB
  short* hs     = (short*)carve((size_t)BSZ * KH * 2);           // 25.17 MB
  short* z1     = (short*)carve((size_t)BSZ * DECD * 2);         //  1.05 MB

  prep_x  <<<(BSZ * KPAD) / 256, 256, 0, stream>>>(enc, oni, ssi, x_bf);
  prep_wih<<<(G4 * KPAD) / 256, 256, 0, stream>>>(W_ih, wih_bf);
  prep_whh<<<(G4 * DECD) / 256, 256, 0, stream>>>(W_hh, whh_bf);

  // x_proj (permuted col layout, biases folded in)
  xproj_k<<<256, 256, 0, stream>>>(x_bf, wih_bf, b_ih, b_hh, xp_p);

  // 24 LSTM steps (grid x = cp so each W_hh panel stays on one XCD's L2)
  step_k<true><<<dim3(64, 4), 256, 0, stream>>>(nullptr, whh_bf, xp_p, c_st, h0, hs_t, 0);
  for (int t = 1; t < PREDT; ++t) {
    short* hr = (t & 1) ? h0 : h1;
    short* hw = (t & 1) ? h1 : h0;
    step_k<false><<<dim3(64, 4), 256, 0, stream>>>(hr, whh_bf, xp_p, c_st, hw, hs_t, t);
  }

  // hs_t -> hs (row-major k = d*24+t)
  transpose_k<<<(BSZ * DECD) / 256, 256, 0, stream>>>(hs_t, hs);

  // head1: split-K=16 partials + reduce(sigmoid) -> z1 bf16  (grid x = bn for L2 locality)
  gemm2_k<1><<<dim3(8, 4, 16), 256, 0, stream>>>(hs, KH, W_l1, KH, 24, KH / 16, nullptr, part, DECD);
  reduce16<<<(BSZ * DECD) / 1024, 256, 0, stream>>>(part, b_l1, z1);

  // head2: out = sigmoid(z1 @ W_l2^T + b_l2)
  gemm2_k<2><<<dim3(8, 4, 1), 256, 0, stream>>>(z1, DECD, W_l2, DECD, 16, DECD, b_l2, out, DECD);
}